// Round 6
// baseline (558.359 us; speedup 1.0000x reference)
//
#include <hip/hip_runtime.h>

// Implicit-GEMM conv2d 3x3 VALID, stride 1, bf16 MFMA — persistent band-blocks,
// rolling LDS window, stage/compute overlap (T14), spill-proofed liveness.
// x: (32,64,112,112) f32  w: (128,64,3,3) f32  bias: (128)  out: (32,128,110,110) f32
// Grid: 32 n x 16 bands = 512 blocks = exactly 2/CU (zero tail). Each block:
// 7 output rows (last band 5). LDS = 4 row-slots x 112 cells x 72 hw (64.5 KB).
// Per row: K-loop (18 kc x 16 MFMA/wave, A dbuf from L2, B dbuf from LDS slots);
// staging loads for row r+3 issued at kc==8 (st live ~half the K-loop only),
// convert+ds_write right after K-loop, barrier, then epilogue (st dead there).

#define CIN   64
#define COUT  128
#define INH   112
#define INW   112
#define HW    (INH*INW)
#define OUTH  110
#define OUTW  110
#define NB    32
#define KTOT  576           // k = (kh*3+kw)*64 + ci
#define NPIX  (NB*OUTH*OUTW)
#define NBANDS 16
#define RPB   7             // rows per band (last band: 5)
#define SLOT  8064          // halfwords per row slot = 112 cells * 72 pitch

typedef __attribute__((ext_vector_type(8))) short short8;     // 8 bf16 (4 VGPRs)
typedef __attribute__((ext_vector_type(4))) float f32x4;

static __device__ __forceinline__ unsigned short f2bf(float f) {
    union { float f; unsigned int u; } v; v.f = f;
    return (unsigned short)((v.u + 0x7FFF + ((v.u >> 16) & 1)) >> 16);  // RNE
}

// ---------- pre-pass: weights -> bf16, fragment-major A_packed ----------
// A_packed halfword index: ((k>>3)*128 + m)*8 + (k&7), k=(kh*3+kw)*64+ci
__global__ __launch_bounds__(256) void prepack_w(const float* __restrict__ w,
                                                 unsigned short* __restrict__ ap) {
    int flat = blockIdx.x * 256 + threadIdx.x;    // 128*576 = 73728 exactly
    int m = flat / KTOT;
    int k = flat - m * KTOT;
    int khw = k >> 6, ci = k & 63;
    int kh = khw / 3, kw = khw - kh * 3;
    float v = w[((m * CIN + ci) * 3 + kh) * 3 + kw];
    ap[((k >> 3) * COUT + m) * 8 + (k & 7)] = f2bf(v);
}

// ---------- main GEMM (persistent band, rolling window) ----------
__global__ __launch_bounds__(256, 2) void conv_gemm(const float* __restrict__ x,
                                                    const unsigned short* __restrict__ ap,
                                                    const float* __restrict__ bias,
                                                    float* __restrict__ out) {
    __shared__ unsigned short ldsB[4 * SLOT];     // 64512 B -> 2 blocks/CU

    // Bijective XCD swizzle over 512 = 8 x 64 blocks.
    const int flat0 = blockIdx.y * NBANDS + blockIdx.x;
    const int flat  = (flat0 & 7) * 64 + (flat0 >> 3);
    const int n    = flat >> 4;
    const int band = flat & 15;
    const int oh0  = band * RPB;
    const int nr   = (band == NBANDS - 1) ? (OUTH - RPB * (NBANDS - 1)) : RPB;  // 5 or 7

    const int t    = threadIdx.x;
    const int lane = t & 63;
    const int wv   = t >> 6;
    const int m_base  = (wv >> 1) * 64;            // co half
    const int px_base = (wv & 1) * 64;             // px half
    const int l16  = lane & 15;
    const int quad = lane >> 4;                    // 0..3

    const short8* A = (const short8*)ap;           // element index (k>>3)*COUT + m

    // ---- staging lane map (conflict-free: exactly 2 lanes/bank on ds_write) ----
    // cip in 0..31 (ci pair), cq in 0..7 -> w = 16i + 2cq + {0,1}
    const int cq  = lane & 7;
    const int cip = wv * 8 + ((lane >> 3) & 3) + 4 * (lane >> 5);
    const float* xrow0 = x + ((size_t)n * CIN + 2 * cip) * HW + (size_t)oh0 * INW;
    unsigned int* ldsW = (unsigned int*)ldsB;

    auto stageIssue = [&](float2* st, int r) {     // load input row oh0+r into regs
        const float* p = xrow0 + (size_t)r * INW;
#pragma unroll
        for (int i = 0; i < 7; ++i) {
            int w0 = 16 * i + 2 * cq;
            st[2 * i]     = *(const float2*)(p + w0);        // ci = 2cip
            st[2 * i + 1] = *(const float2*)(p + HW + w0);   // ci = 2cip+1
        }
    };
    auto stageWrite = [&](const float2* st, int slot) {      // convert + LDS write
        unsigned int* dst = ldsW + slot * (SLOT / 2) + cip;
#pragma unroll
        for (int i = 0; i < 7; ++i) {
            int w0 = 16 * i + 2 * cq;
            float2 va = st[2 * i], vb = st[2 * i + 1];
            dst[(w0)     * 36] = (unsigned int)f2bf(va.x) | ((unsigned int)f2bf(vb.x) << 16);
            dst[(w0 + 1) * 36] = (unsigned int)f2bf(va.y) | ((unsigned int)f2bf(vb.y) << 16);
        }
    };

    auto loadA = [&](short8* a, int kc) {
#pragma unroll
        for (int i = 0; i < 4; ++i)                // lane k-run = k&7 contiguous
            a[i] = A[(kc * 4 + quad) * COUT + (m_base + i * 16 + l16)];
    };

    {   // prologue: rows 0..2 -> slots 0..2 (short st liveness, reused buffer)
        float2 st[14];
        for (int r = 0; r < 3; ++r) { stageIssue(st, r); stageWrite(st, r); }
    }
    __syncthreads();

    for (int r = 0; r < nr; ++r) {
        const bool doStage = (r + 3 < nr + 2);     // rows needed: 0..nr+1
        const int sb0 = ((r    ) & 3) * SLOT;
        const int sb1 = ((r + 1) & 3) * SLOT;
        const int sb2 = ((r + 2) & 3) * SLOT;

        auto loadB = [&](short8* b, int kc) {
            const int khw = kc >> 1;
            const int kh = khw / 3, kw = khw - kh * 3;   // compile-time after unroll
            const int sb = (kh == 0) ? sb0 : (kh == 1) ? sb1 : sb2;
            const int ci0 = (kc & 1) * 32 + quad * 8;
#pragma unroll
            for (int j = 0; j < 4; ++j) {
                int ow = px_base + j * 16 + l16;
                ow = (ow < OUTW) ? ow : (OUTW - 1);      // clamp garbage cols
                b[j] = *(const short8*)&ldsB[sb + (ow + kw) * 72 + ci0];
            }
        };

        short8 a0[4], a1[4], b0[4], b1[4];
        float2 st[14];                             // live only kc>=8 .. stageWrite
        f32x4 acc[4][4] = {};

        loadA(a0, 0);
        loadA(a1, 1);
        loadB(b0, 0);
        loadB(b1, 1);

#pragma unroll
        for (int kc = 0; kc < 18; kc += 2) {
            if (kc == 8 && doStage) stageIssue(st, r + 3);   // T14: issue mid-loop
            __builtin_amdgcn_s_setprio(1);
#pragma unroll
            for (int i = 0; i < 4; ++i)
#pragma unroll
                for (int j = 0; j < 4; ++j)
                    acc[i][j] = __builtin_amdgcn_mfma_f32_16x16x32_bf16(a0[i], b0[j], acc[i][j], 0, 0, 0);
            __builtin_amdgcn_s_setprio(0);
            if (kc + 2 < 18) { loadA(a0, kc + 2); loadB(b0, kc + 2); }
            __builtin_amdgcn_s_setprio(1);
#pragma unroll
            for (int i = 0; i < 4; ++i)
#pragma unroll
                for (int j = 0; j < 4; ++j)
                    acc[i][j] = __builtin_amdgcn_mfma_f32_16x16x32_bf16(a1[i], b1[j], acc[i][j], 0, 0, 0);
            __builtin_amdgcn_s_setprio(0);
            if (kc + 3 < 18) { loadA(a1, kc + 3); loadB(b1, kc + 3); }
        }

        if (doStage) stageWrite(st, (r + 3) & 3);  // st dies here, before epilogue
        __syncthreads();                           // slots ready for row r+1

        // epilogue: C/D layout (verified m89): col = lane&15 -> ow, row = quad*4+reg -> co
        const int ohr = oh0 + r;
#pragma unroll
        for (int i = 0; i < 4; ++i) {
            const int co = m_base + i * 16 + quad * 4;
#pragma unroll
            for (int j = 0; j < 4; ++j) {
                const int ow = px_base + j * 16 + l16;
                if (ow < OUTW) {
                    const size_t ob = (((size_t)n * COUT + co) * OUTH + ohr) * OUTW + ow;
#pragma unroll
                    for (int rr = 0; rr < 4; ++rr)
                        out[ob + (size_t)rr * (OUTH * OUTW)] = acc[i][j][rr] + bias[co + rr];
                }
            }
        }
    }
}

// ---------- fallback (round-1 direct conv) if ws too small ----------
#define TCO 16
__global__ __launch_bounds__(256) void conv_direct(const float* __restrict__ x,
                                                   const float* __restrict__ w,
                                                   const float* __restrict__ bias,
                                                   float* __restrict__ out) {
    int p = blockIdx.x * 256 + threadIdx.x;
    const int co0 = blockIdx.y * TCO;
    const bool valid = p < NPIX;
    if (!valid) p = 0;
    const int n = p / (OUTH * OUTW);
    const int rem = p - n * (OUTH * OUTW);
    const int oh = rem / OUTW;
    const int ow = rem - oh * OUTW;
    float acc[TCO];
#pragma unroll
    for (int t = 0; t < TCO; ++t) acc[t] = bias[co0 + t];
    const float* xb = x + ((size_t)n * CIN) * HW + (size_t)oh * INW + ow;
    const float* wb = w + (size_t)co0 * CIN * 9;
    for (int ci = 0; ci < CIN; ++ci) {
        const float* xp = xb + (size_t)ci * HW;
        const float* wp = wb + ci * 9;
#pragma unroll
        for (int kh = 0; kh < 3; ++kh) {
            const float x0 = xp[kh * INW + 0];
            const float x1 = xp[kh * INW + 1];
            const float x2 = xp[kh * INW + 2];
#pragma unroll
            for (int t = 0; t < TCO; ++t) {
                const float* wt = wp + t * (CIN * 9) + kh * 3;
                acc[t] = fmaf(x0, wt[0], acc[t]);
                acc[t] = fmaf(x1, wt[1], acc[t]);
                acc[t] = fmaf(x2, wt[2], acc[t]);
            }
        }
    }
    if (valid) {
        const size_t ob = ((size_t)n * COUT + co0) * (OUTH * OUTW) + (size_t)oh * OUTW + ow;
#pragma unroll
        for (int t = 0; t < TCO; ++t)
            out[ob + (size_t)t * (OUTH * OUTW)] = acc[t];
    }
}

extern "C" void kernel_launch(void* const* d_in, const int* in_sizes, int n_in,
                              void* d_out, int out_size, void* d_ws, size_t ws_size,
                              hipStream_t stream) {
    const float* x    = (const float*)d_in[0];
    const float* w    = (const float*)d_in[1];
    const float* bias = (const float*)d_in[2];
    float* out        = (float*)d_out;

    const size_t ap_bytes = (size_t)COUT * KTOT * 2;             // 147,456

    if (ws_size >= ap_bytes) {
        unsigned short* apck = (unsigned short*)d_ws;
        prepack_w<<<288, 256, 0, stream>>>(w, apck);
        conv_gemm<<<dim3(NBANDS, NB), 256, 0, stream>>>(x, apck, bias, out);
    } else {
        dim3 grid((NPIX + 255) / 256, COUT / TCO);
        conv_direct<<<grid, dim3(256), 0, stream>>>(x, w, bias, out);
    }
}

// Round 7
// 508.503 us; speedup vs baseline: 1.0980x; 1.0980x over previous
//
#include <hip/hip_runtime.h>

// Implicit-GEMM conv2d 3x3 VALID, stride 1, bf16 MFMA — persistent band-blocks,
// rolling LDS window, DIRECT staging (no register staging buffer -> no spill).
// x: (32,64,112,112) f32  w: (128,64,3,3) f32  bias: (128)  out: (32,128,110,110) f32
// Grid: 32 n x 16 bands = 512 blocks = exactly 2/CU (zero tail). Each block:
// 7 output rows (last band 5). LDS = 4 row-slots x 112 cells x 72 hw (64.5 KB).
// Per row: K-loop (18 kc x 16 MFMA/wave, A dbuf from L2, B dbuf from LDS slots);
// at kc==8 the next input row is staged DIRECTLY (load->f2bf->ds_write burst,
// transient regs only); barrier after K-loop; epilogue touches no LDS.

#define CIN   64
#define COUT  128
#define INH   112
#define INW   112
#define HW    (INH*INW)
#define OUTH  110
#define OUTW  110
#define NB    32
#define KTOT  576           // k = (kh*3+kw)*64 + ci
#define NPIX  (NB*OUTH*OUTW)
#define NBANDS 16
#define RPB   7             // rows per band (last band: 5)
#define SLOT  8064          // halfwords per row slot = 112 cells * 72 pitch

typedef __attribute__((ext_vector_type(8))) short short8;     // 8 bf16 (4 VGPRs)
typedef __attribute__((ext_vector_type(4))) float f32x4;

static __device__ __forceinline__ unsigned short f2bf(float f) {
    union { float f; unsigned int u; } v; v.f = f;
    return (unsigned short)((v.u + 0x7FFF + ((v.u >> 16) & 1)) >> 16);  // RNE
}

// ---------- pre-pass: weights -> bf16, fragment-major A_packed ----------
// A_packed halfword index: ((k>>3)*128 + m)*8 + (k&7), k=(kh*3+kw)*64+ci
__global__ __launch_bounds__(256) void prepack_w(const float* __restrict__ w,
                                                 unsigned short* __restrict__ ap) {
    int flat = blockIdx.x * 256 + threadIdx.x;    // 128*576 = 73728 exactly
    int m = flat / KTOT;
    int k = flat - m * KTOT;
    int khw = k >> 6, ci = k & 63;
    int kh = khw / 3, kw = khw - kh * 3;
    float v = w[((m * CIN + ci) * 3 + kh) * 3 + kw];
    ap[((k >> 3) * COUT + m) * 8 + (k & 7)] = f2bf(v);
}

// ---------- main GEMM (persistent band, rolling window, direct staging) ----------
__global__ __launch_bounds__(256, 2) void conv_gemm(const float* __restrict__ x,
                                                    const unsigned short* __restrict__ ap,
                                                    const float* __restrict__ bias,
                                                    float* __restrict__ out) {
    __shared__ unsigned short ldsB[4 * SLOT];     // 64512 B -> 2 blocks/CU

    // Bijective XCD swizzle over 512 = 8 x 64 blocks: each XCD gets 4 whole
    // images (consecutive bands of one n adjacent in time -> row reuse in L2).
    const int flat0 = blockIdx.y * NBANDS + blockIdx.x;
    const int flat  = (flat0 & 7) * 64 + (flat0 >> 3);
    const int n    = flat >> 4;
    const int band = flat & 15;
    const int oh0  = band * RPB;
    const int nr   = (band == NBANDS - 1) ? (OUTH - RPB * (NBANDS - 1)) : RPB;  // 5 or 7

    const int t    = threadIdx.x;
    const int lane = t & 63;
    const int wv   = t >> 6;
    const int m_base  = (wv >> 1) * 64;            // co half
    const int px_base = (wv & 1) * 64;             // px half
    const int l16  = lane & 15;
    const int quad = lane >> 4;                    // 0..3

    const short8* A = (const short8*)ap;           // element index (k>>3)*COUT + m

    // ---- staging lane map (ds_write: exactly 2 lanes/bank = free) ----
    // cip in 0..31 (ci pair), cq in 0..7 -> w = 16i + 2cq + {0,1}
    const int cq  = lane & 7;
    const int cip = wv * 8 + ((lane >> 3) & 3) + 4 * (lane >> 5);
    const float* xrow0 = x + ((size_t)n * CIN + 2 * cip) * HW + (size_t)oh0 * INW;
    unsigned int* ldsW = (unsigned int*)ldsB;

    // Direct stage: load input row oh0+r, convert, write slot. Transient regs only.
    auto stageRow = [&](int r, int slot) {
        const float* p = xrow0 + (size_t)r * INW;
        unsigned int* dst = ldsW + slot * (SLOT / 2) + cip;
#pragma unroll
        for (int i = 0; i < 7; ++i) {
            int w0 = 16 * i + 2 * cq;
            float2 va = *(const float2*)(p + w0);        // ci = 2cip
            float2 vb = *(const float2*)(p + HW + w0);   // ci = 2cip+1
            dst[(w0)     * 36] = (unsigned int)f2bf(va.x) | ((unsigned int)f2bf(vb.x) << 16);
            dst[(w0 + 1) * 36] = (unsigned int)f2bf(va.y) | ((unsigned int)f2bf(vb.y) << 16);
        }
    };

    auto loadA = [&](short8* a, int kc) {
#pragma unroll
        for (int i = 0; i < 4; ++i)                // lane k-run = k&7 contiguous
            a[i] = A[(kc * 4 + quad) * COUT + (m_base + i * 16 + l16)];
    };

    for (int r = 0; r < 3; ++r) stageRow(r, r);    // prologue: rows 0..2 -> slots 0..2
    __syncthreads();

    for (int r = 0; r < nr; ++r) {
        const bool doStage = (r + 3 < nr + 2);     // rows needed: 0..nr+1
        const int sb0 = ((r    ) & 3) * SLOT;
        const int sb1 = ((r + 1) & 3) * SLOT;
        const int sb2 = ((r + 2) & 3) * SLOT;

        auto loadB = [&](short8* b, int kc) {
            const int khw = kc >> 1;
            const int kh = khw / 3, kw = khw - kh * 3;   // compile-time after unroll
            const int sb = (kh == 0) ? sb0 : (kh == 1) ? sb1 : sb2;
            const int ci0 = (kc & 1) * 32 + quad * 8;
#pragma unroll
            for (int j = 0; j < 4; ++j) {
                int ow = px_base + j * 16 + l16;
                ow = (ow < OUTW) ? ow : (OUTW - 1);      // clamp garbage cols
                b[j] = *(const short8*)&ldsB[sb + (ow + kw) * 72 + ci0];
            }
        };

        short8 a0[4], a1[4], b0[4], b1[4];
        f32x4 acc[4][4] = {};

        loadA(a0, 0);
        loadA(a1, 1);
        loadB(b0, 0);
        loadB(b1, 1);

#pragma unroll
        for (int kc = 0; kc < 18; kc += 2) {
            __builtin_amdgcn_s_setprio(1);
#pragma unroll
            for (int i = 0; i < 4; ++i)
#pragma unroll
                for (int j = 0; j < 4; ++j)
                    acc[i][j] = __builtin_amdgcn_mfma_f32_16x16x32_bf16(a0[i], b0[j], acc[i][j], 0, 0, 0);
            __builtin_amdgcn_s_setprio(0);
            if (kc == 8 && doStage) stageRow(r + 3, (r + 3) & 3);   // direct, transient
            if (kc + 2 < 18) { loadA(a0, kc + 2); loadB(b0, kc + 2); }
            __builtin_amdgcn_s_setprio(1);
#pragma unroll
            for (int i = 0; i < 4; ++i)
#pragma unroll
                for (int j = 0; j < 4; ++j)
                    acc[i][j] = __builtin_amdgcn_mfma_f32_16x16x32_bf16(a1[i], b1[j], acc[i][j], 0, 0, 0);
            __builtin_amdgcn_s_setprio(0);
            if (kc + 3 < 18) { loadA(a1, kc + 3); loadB(b1, kc + 3); }
        }

        __syncthreads();                           // slot (r+3)&3 ready for row r+1

        // epilogue: C/D layout (verified m89): col = lane&15 -> ow, row = quad*4+reg -> co
        const int ohr = oh0 + r;
#pragma unroll
        for (int i = 0; i < 4; ++i) {
            const int co = m_base + i * 16 + quad * 4;
#pragma unroll
            for (int j = 0; j < 4; ++j) {
                const int ow = px_base + j * 16 + l16;
                if (ow < OUTW) {
                    const size_t ob = (((size_t)n * COUT + co) * OUTH + ohr) * OUTW + ow;
#pragma unroll
                    for (int rr = 0; rr < 4; ++rr)
                        out[ob + (size_t)rr * (OUTH * OUTW)] = acc[i][j][rr] + bias[co + rr];
                }
            }
        }
    }
}

// ---------- fallback (round-1 direct conv) if ws too small ----------
#define TCO 16
__global__ __launch_bounds__(256) void conv_direct(const float* __restrict__ x,
                                                   const float* __restrict__ w,
                                                   const float* __restrict__ bias,
                                                   float* __restrict__ out) {
    int p = blockIdx.x * 256 + threadIdx.x;
    const int co0 = blockIdx.y * TCO;
    const bool valid = p < NPIX;
    if (!valid) p = 0;
    const int n = p / (OUTH * OUTW);
    const int rem = p - n * (OUTH * OUTW);
    const int oh = rem / OUTW;
    const int ow = rem - oh * OUTW;
    float acc[TCO];
#pragma unroll
    for (int t = 0; t < TCO; ++t) acc[t] = bias[co0 + t];
    const float* xb = x + ((size_t)n * CIN) * HW + (size_t)oh * INW + ow;
    const float* wb = w + (size_t)co0 * CIN * 9;
    for (int ci = 0; ci < CIN; ++ci) {
        const float* xp = xb + (size_t)ci * HW;
        const float* wp = wb + ci * 9;
#pragma unroll
        for (int kh = 0; kh < 3; ++kh) {
            const float x0 = xp[kh * INW + 0];
            const float x1 = xp[kh * INW + 1];
            const float x2 = xp[kh * INW + 2];
#pragma unroll
            for (int t = 0; t < TCO; ++t) {
                const float* wt = wp + t * (CIN * 9) + kh * 3;
                acc[t] = fmaf(x0, wt[0], acc[t]);
                acc[t] = fmaf(x1, wt[1], acc[t]);
                acc[t] = fmaf(x2, wt[2], acc[t]);
            }
        }
    }
    if (valid) {
        const size_t ob = ((size_t)n * COUT + co0) * (OUTH * OUTW) + (size_t)oh * OUTW + ow;
#pragma unroll
        for (int t = 0; t < TCO; ++t)
            out[ob + (size_t)t * (OUTH * OUTW)] = acc[t];
    }
}

extern "C" void kernel_launch(void* const* d_in, const int* in_sizes, int n_in,
                              void* d_out, int out_size, void* d_ws, size_t ws_size,
                              hipStream_t stream) {
    const float* x    = (const float*)d_in[0];
    const float* w    = (const float*)d_in[1];
    const float* bias = (const float*)d_in[2];
    float* out        = (float*)d_out;

    const size_t ap_bytes = (size_t)COUT * KTOT * 2;             // 147,456

    if (ws_size >= ap_bytes) {
        unsigned short* apck = (unsigned short*)d_ws;
        prepack_w<<<288, 256, 0, stream>>>(w, apck);
        conv_gemm<<<dim3(NBANDS, NB), 256, 0, stream>>>(x, apck, bias, out);
    } else {
        dim3 grid((NPIX + 255) / 256, COUT / TCO);
        conv_direct<<<grid, dim3(256), 0, stream>>>(x, w, bias, out);
    }
}

// Round 8
// 325.006 us; speedup vs baseline: 1.7180x; 1.5646x over previous
//
#include <hip/hip_runtime.h>

// Implicit-GEMM conv2d 3x3 VALID, stride 1, via bf16 MFMA — fused conversion, fat waves,
// two-phase staging overlap. (= round-4 best-measured kernel + split staging.)
// x: (32,64,112,112) f32  w: (128,64,3,3) f32  bias: (128)  out: (32,128,110,110) f32
// GEMM view: M=Cout=128, K=576, N=pixels. Per block: one n, TWO output rows (oh0,oh0+1),
// tile 128co x 256px. Per wave: 64co x 128px -> 32-MFMA runs per K-chunk hide load latency;
// A dbuf from L2, B half-buffers from LDS. K-order is (kh,kw)-major: kc 0-5 read only
// input rows 0-1, so rows 0-1 are staged pre-barrier, rows 2-3 are staged between the
// kc=0..5 and kc=6..17 phases (transient burst, overlapped via TLP), second barrier.

#define CIN   64
#define COUT  128
#define INH   112
#define INW   112
#define HW    (INH*INW)
#define OUTH  110
#define OUTW  110
#define NB    32
#define KTOT  576           // k = (kh*3+kw)*64 + ci
#define NPIX  (NB*OUTH*OUTW)

typedef __attribute__((ext_vector_type(8))) short short8;     // 8 bf16 (4 VGPRs)
typedef __attribute__((ext_vector_type(4))) float f32x4;

static __device__ __forceinline__ unsigned short f2bf(float f) {
    union { float f; unsigned int u; } v; v.f = f;
    return (unsigned short)((v.u + 0x7FFF + ((v.u >> 16) & 1)) >> 16);  // RNE
}

// ---------- pre-pass: weights -> bf16, fragment-major A_packed ----------
// A_packed halfword index: ((k>>3)*128 + m)*8 + (k&7), k=(kh*3+kw)*64+ci
__global__ __launch_bounds__(256) void prepack_w(const float* __restrict__ w,
                                                 unsigned short* __restrict__ ap) {
    int flat = blockIdx.x * 256 + threadIdx.x;    // 128*576 = 73728 exactly
    int m = flat / KTOT;
    int k = flat - m * KTOT;
    int khw = k >> 6, ci = k & 63;
    int kh = khw / 3, kw = khw - kh * 3;
    float v = w[((m * CIN + ci) * 3 + kh) * 3 + kw];
    ap[((k >> 3) * COUT + m) * 8 + (k & 7)] = f2bf(v);
}

// ---------- main GEMM (fused x-conversion, 2 output rows per block) ----------
__global__ __launch_bounds__(256, 2) void conv_gemm(const float* __restrict__ x,
                                                    const unsigned short* __restrict__ ap,
                                                    const float* __restrict__ bias,
                                                    float* __restrict__ out) {
    // B tile: 4 input rows (oh0..oh0+3), 448 cells x 72 halfwords (pitch 72 ->
    // b128 read lane stride 144B = 2-way bank alias = free). 64.5 KB -> 2 blocks/CU.
    __shared__ unsigned short ldsB[32256];

    // Bijective XCD swizzle (1760 blocks = 8 x 220): same-n adjacent row-pairs
    // (sharing input rows) land on the same XCD's L2.
    const int flat0 = blockIdx.y * 55 + blockIdx.x;
    const int flat  = (flat0 & 7) * 220 + (flat0 >> 3);
    const int n   = flat / 55;
    const int ohp = flat - n * 55;
    const int oh0 = ohp * 2;
    const int t   = threadIdx.x;

    const int lane = t & 63;
    const int wv   = t >> 6;
    const int m_base  = (wv >> 1) * 64;            // co half
    const int px_base = (wv & 1) * 128;            // px half (128 px = 2 orow x 64)
    const int l16  = lane & 15;
    const int quad = lane >> 4;                    // 0..3

    const short8* A = (const short8*)ap;           // index kb*128 + m

    auto loadA = [&](short8* a, int kc) {
#pragma unroll
        for (int i = 0; i < 4; ++i)                // lane k-run = k&7 contiguous
            a[i] = A[(kc * 4 + quad) * COUT + (m_base + i * 16 + l16)];
    };
    // h = 0: j 0..3, h = 1: j 4..7.  px = px_base + j*16 + l16 (never crosses 128-bdry)
    auto loadBh = [&](short8* b, int kc, int h) {
        const int khw = kc >> 1;
        const int kh = khw / 3, kw = khw - kh * 3; // compile-time after unroll
        const int ci0 = (kc & 1) * 32 + quad * 8;
#pragma unroll
        for (int jj = 0; jj < 4; ++jj) {
            int px = px_base + (h * 4 + jj) * 16 + l16;
            int orow = px >> 7;
            int ow = px & 127;
            ow = (ow < OUTW) ? ow : (OUTW - 1);    // clamp garbage cols: stay in 448 cells
            b[jj] = *(const short8*)&ldsB[((orow + kh) * INW + ow + kw) * 72 + ci0];
        }
    };

    // ---- staging lane map (ds_write: exactly 2 lanes/bank = free) ----
    // cip in 0..31 (ci pair), cq in 0..7 -> w = 16i + 2cq + {0,1}; 64B-coalesced reads.
    const int cq  = lane & 7;
    const int cip = wv * 8 + ((lane >> 3) & 3) + 4 * (lane >> 5);
    const float* xrow0 = x + ((size_t)n * CIN + 2 * cip) * HW + (size_t)oh0 * INW;
    unsigned int* ldsW = (unsigned int*)ldsB;

    auto stageRow = [&](int r) {                   // stage input row oh0+r (transient regs)
        const float* p = xrow0 + (size_t)r * INW;
        unsigned int* dst = ldsW + r * (112 * 36) + cip;
#pragma unroll
        for (int i = 0; i < 7; ++i) {
            int w0 = 16 * i + 2 * cq;
            float2 va = *(const float2*)(p + w0);        // ci = 2cip
            float2 vb = *(const float2*)(p + HW + w0);   // ci = 2cip+1
            dst[(w0)     * 36] = (unsigned int)f2bf(va.x) | ((unsigned int)f2bf(vb.x) << 16);
            dst[(w0 + 1) * 36] = (unsigned int)f2bf(va.y) | ((unsigned int)f2bf(vb.y) << 16);
        }
    };

    short8 a0[4], a1[4], bA[4], bB[4];
    loadA(a0, 0);                                  // L2 latency hides under staging

    stageRow(0);                                   // phase-A needs rows 0-1 only (kh=0)
    stageRow(1);
    loadA(a1, 1);
    __syncthreads();                               // barrier 1

    f32x4 acc[4][8] = {};                          // [m-tile][px-tile], 128 AGPR
    loadBh(bA, 0, 0);

    // ---- phase A: kc 0..5 (kh = 0) ----
#pragma unroll
    for (int kc = 0; kc < 6; kc += 2) {
        loadBh(bB, kc, 1);
        __builtin_amdgcn_s_setprio(1);
#pragma unroll
        for (int i = 0; i < 4; ++i)
#pragma unroll
            for (int jj = 0; jj < 4; ++jj)
                acc[i][jj] = __builtin_amdgcn_mfma_f32_16x16x32_bf16(a0[i], bA[jj], acc[i][jj], 0, 0, 0);
        __builtin_amdgcn_s_setprio(0);
        loadBh(bA, kc + 1, 0);
        __builtin_amdgcn_s_setprio(1);
#pragma unroll
        for (int i = 0; i < 4; ++i)
#pragma unroll
            for (int jj = 0; jj < 4; ++jj)
                acc[i][4 + jj] = __builtin_amdgcn_mfma_f32_16x16x32_bf16(a0[i], bB[jj], acc[i][4 + jj], 0, 0, 0);
        __builtin_amdgcn_s_setprio(0);
        loadA(a0, kc + 2);
        loadBh(bB, kc + 1, 1);
        __builtin_amdgcn_s_setprio(1);
#pragma unroll
        for (int i = 0; i < 4; ++i)
#pragma unroll
            for (int jj = 0; jj < 4; ++jj)
                acc[i][jj] = __builtin_amdgcn_mfma_f32_16x16x32_bf16(a1[i], bA[jj], acc[i][jj], 0, 0, 0);
        __builtin_amdgcn_s_setprio(0);
        if (kc + 2 < 6) loadBh(bA, kc + 2, 0);     // kc=4: suppressed (kc+2=6 is kh=1)
        __builtin_amdgcn_s_setprio(1);
#pragma unroll
        for (int i = 0; i < 4; ++i)
#pragma unroll
            for (int jj = 0; jj < 4; ++jj)
                acc[i][4 + jj] = __builtin_amdgcn_mfma_f32_16x16x32_bf16(a1[i], bB[jj], acc[i][4 + jj], 0, 0, 0);
        __builtin_amdgcn_s_setprio(0);
        loadA(a1, kc + 3);
    }

    stageRow(2);                                   // rows 2-3 for kh=1,2; overlapped
    stageRow(3);                                   // with other waves'/block's phase A
    __syncthreads();                               // barrier 2

    loadBh(bA, 6, 0);

    // ---- phase B: kc 6..17 (kh = 1,2) ----
#pragma unroll
    for (int kc = 6; kc < 18; kc += 2) {
        loadBh(bB, kc, 1);
        __builtin_amdgcn_s_setprio(1);
#pragma unroll
        for (int i = 0; i < 4; ++i)
#pragma unroll
            for (int jj = 0; jj < 4; ++jj)
                acc[i][jj] = __builtin_amdgcn_mfma_f32_16x16x32_bf16(a0[i], bA[jj], acc[i][jj], 0, 0, 0);
        __builtin_amdgcn_s_setprio(0);
        loadBh(bA, kc + 1, 0);
        __builtin_amdgcn_s_setprio(1);
#pragma unroll
        for (int i = 0; i < 4; ++i)
#pragma unroll
            for (int jj = 0; jj < 4; ++jj)
                acc[i][4 + jj] = __builtin_amdgcn_mfma_f32_16x16x32_bf16(a0[i], bB[jj], acc[i][4 + jj], 0, 0, 0);
        __builtin_amdgcn_s_setprio(0);
        if (kc + 2 < 18) loadA(a0, kc + 2);
        loadBh(bB, kc + 1, 1);
        __builtin_amdgcn_s_setprio(1);
#pragma unroll
        for (int i = 0; i < 4; ++i)
#pragma unroll
            for (int jj = 0; jj < 4; ++jj)
                acc[i][jj] = __builtin_amdgcn_mfma_f32_16x16x32_bf16(a1[i], bA[jj], acc[i][jj], 0, 0, 0);
        __builtin_amdgcn_s_setprio(0);
        if (kc + 2 < 18) loadBh(bA, kc + 2, 0);
        __builtin_amdgcn_s_setprio(1);
#pragma unroll
        for (int i = 0; i < 4; ++i)
#pragma unroll
            for (int jj = 0; jj < 4; ++jj)
                acc[i][4 + jj] = __builtin_amdgcn_mfma_f32_16x16x32_bf16(a1[i], bB[jj], acc[i][4 + jj], 0, 0, 0);
        __builtin_amdgcn_s_setprio(0);
        if (kc + 3 < 18) loadA(a1, kc + 3);
    }

    // C/D layout (verified m89): col = lane&15 -> px, row = quad*4 + reg -> co
#pragma unroll
    for (int i = 0; i < 4; ++i) {
        const int co = m_base + i * 16 + quad * 4;
#pragma unroll
        for (int j = 0; j < 8; ++j) {
            const int px = px_base + j * 16 + l16;
            const int orow = px >> 7;
            const int ow = px & 127;
            if (ow < OUTW) {
                const size_t ob = (((size_t)n * COUT + co) * OUTH + (oh0 + orow)) * OUTW + ow;
#pragma unroll
                for (int r = 0; r < 4; ++r)
                    out[ob + (size_t)r * (OUTH * OUTW)] = acc[i][j][r] + bias[co + r];
            }
        }
    }
}

// ---------- fallback (round-1 direct conv) if ws too small ----------
#define TCO 16
__global__ __launch_bounds__(256) void conv_direct(const float* __restrict__ x,
                                                   const float* __restrict__ w,
                                                   const float* __restrict__ bias,
                                                   float* __restrict__ out) {
    int p = blockIdx.x * 256 + threadIdx.x;
    const int co0 = blockIdx.y * TCO;
    const bool valid = p < NPIX;
    if (!valid) p = 0;
    const int n = p / (OUTH * OUTW);
    const int rem = p - n * (OUTH * OUTW);
    const int oh = rem / OUTW;
    const int ow = rem - oh * OUTW;
    float acc[TCO];
#pragma unroll
    for (int t = 0; t < TCO; ++t) acc[t] = bias[co0 + t];
    const float* xb = x + ((size_t)n * CIN) * HW + (size_t)oh * INW + ow;
    const float* wb = w + (size_t)co0 * CIN * 9;
    for (int ci = 0; ci < CIN; ++ci) {
        const float* xp = xb + (size_t)ci * HW;
        const float* wp = wb + ci * 9;
#pragma unroll
        for (int kh = 0; kh < 3; ++kh) {
            const float x0 = xp[kh * INW + 0];
            const float x1 = xp[kh * INW + 1];
            const float x2 = xp[kh * INW + 2];
#pragma unroll
            for (int t = 0; t < TCO; ++t) {
                const float* wt = wp + t * (CIN * 9) + kh * 3;
                acc[t] = fmaf(x0, wt[0], acc[t]);
                acc[t] = fmaf(x1, wt[1], acc[t]);
                acc[t] = fmaf(x2, wt[2], acc[t]);
            }
        }
    }
    if (valid) {
        const size_t ob = ((size_t)n * COUT + co0) * (OUTH * OUTW) + (size_t)oh * OUTW + ow;
#pragma unroll
        for (int t = 0; t < TCO; ++t)
            out[ob + (size_t)t * (OUTH * OUTW)] = acc[t];
    }
}

extern "C" void kernel_launch(void* const* d_in, const int* in_sizes, int n_in,
                              void* d_out, int out_size, void* d_ws, size_t ws_size,
                              hipStream_t stream) {
    const float* x    = (const float*)d_in[0];
    const float* w    = (const float*)d_in[1];
    const float* bias = (const float*)d_in[2];
    float* out        = (float*)d_out;

    const size_t ap_bytes = (size_t)COUT * KTOT * 2;             // 147,456

    if (ws_size >= ap_bytes) {
        unsigned short* apck = (unsigned short*)d_ws;
        prepack_w<<<288, 256, 0, stream>>>(w, apck);
        conv_gemm<<<dim3(55, NB), 256, 0, stream>>>(x, apck, bias, out);
    } else {
        dim3 grid((NPIX + 255) / 256, COUT / TCO);
        conv_direct<<<grid, dim3(256), 0, stream>>>(x, w, bias, out);
    }
}